// Round 6
// baseline (1510.766 us; speedup 1.0000x reference)
//
#include <hip/hip_runtime.h>
#include <cmath>

#define HID 64
#define IN_C 128

__device__ __forceinline__ float rl(float v, int k) {
    return __uint_as_float(__builtin_amdgcn_readlane(__float_as_uint(v), k));
}
__device__ __forceinline__ float bflo(unsigned u) { return __uint_as_float(u << 16); }
__device__ __forceinline__ float bfhi(unsigned u) { return __uint_as_float(u & 0xffff0000u); }
// pack two floats to bf16 pair with round-to-nearest-even
__device__ __forceinline__ unsigned bfpack(float lo, float hi) {
    unsigned a = __float_as_uint(lo), b = __float_as_uint(hi);
    a = (a + 0x7fffu + ((a >> 16) & 1u)) >> 16;
    b = (b + 0x7fffu + ((b >> 16) & 1u)) & 0xffff0000u;
    return a | b;
}

// ---- VALU cross-lane helpers (keep off the LDS pipe) --------------------
// xor-8 within 16-lane row: DPP row_ror:8 (0x128) — rotation, xor-symmetric
__device__ __forceinline__ float xadd8(float x) {
    int t = __builtin_amdgcn_update_dpp(0, __float_as_int(x), 0x128, 0xF, 0xF, true);
    return x + __int_as_float(t);
}
#if __has_builtin(__builtin_amdgcn_permlane16_swap)
typedef unsigned uvec2 __attribute__((ext_vector_type(2)));
__device__ __forceinline__ float xadd16(float x) {
    uvec2 r = __builtin_amdgcn_permlane16_swap(__float_as_uint(x), __float_as_uint(x), false, false);
    return __uint_as_float(r[0]) + __uint_as_float(r[1]);
}
#else
__device__ __forceinline__ float xadd16(float x) { return x + __shfl_xor(x, 16); }
#endif
#if __has_builtin(__builtin_amdgcn_permlane32_swap)
typedef unsigned uvec2b __attribute__((ext_vector_type(2)));
__device__ __forceinline__ float xadd32(float x) {
    uvec2b r = __builtin_amdgcn_permlane32_swap(__float_as_uint(x), __float_as_uint(x), false, false);
    return __uint_as_float(r[0]) + __uint_as_float(r[1]);
}
#else
__device__ __forceinline__ float xadd32(float x) { return x + __shfl_xor(x, 32); }
#endif
// value from lane^1: DPP quad_perm [1,0,3,2] = 0xB1 (direction-unambiguous)
__device__ __forceinline__ float pairswap(float x) {
    int t = __builtin_amdgcn_update_dpp(0, __float_as_int(x), 0xB1, 0xF, 0xF, true);
    return __int_as_float(t);
}

// ---- CSR build ----------------------------------------------------------

__global__ void k_hist(const int* __restrict__ dst, int* __restrict__ counts, int E) {
    int e = blockIdx.x * blockDim.x + threadIdx.x;
    if (e < E) atomicAdd(&counts[dst[e]], 1);
}

__global__ void k_scan_block(const int* __restrict__ counts, int* __restrict__ row_ptr,
                             int* __restrict__ chunk_sums, int n) {
    __shared__ int s[1024];
    int i = blockIdx.x * 1024 + threadIdx.x;
    int v = (i < n) ? counts[i] : 0;
    s[threadIdx.x] = v;
    __syncthreads();
    for (int off = 1; off < 1024; off <<= 1) {
        int t = (threadIdx.x >= off) ? s[threadIdx.x - off] : 0;
        __syncthreads();
        s[threadIdx.x] += t;
        __syncthreads();
    }
    if (i < n) row_ptr[i] = s[threadIdx.x] - v;   // exclusive
    if (threadIdx.x == 1023) chunk_sums[blockIdx.x] = s[1023];
}

__global__ void k_scan_fix(int* __restrict__ row_ptr, const int* __restrict__ chunk_sums,
                           int n, int total) {
    __shared__ int base_s;
    if (threadIdx.x == 0) {
        int b = 0;
        for (int c = 0; c < (int)blockIdx.x; ++c) b += chunk_sums[c];
        base_s = b;
    }
    __syncthreads();
    int i = blockIdx.x * 1024 + threadIdx.x;
    if (i < n) row_ptr[i] += base_s;
    if (i == 0) row_ptr[n] = total;
}

__global__ void k_fill(const int* __restrict__ src, const int* __restrict__ dst,
                       const int* __restrict__ row_ptr, int* __restrict__ cursor,
                       int* __restrict__ col_idx, int E) {
    int e = blockIdx.x * blockDim.x + threadIdx.x;
    if (e < E) {
        int d = dst[e];
        int pos = row_ptr[d] + atomicAdd(&cursor[d], 1);
        col_idx[pos] = src[e];
    }
}

// ---- input projection: h0(bf16) = relu(x @ lin0_w^T) --------------------
__global__ __launch_bounds__(256) void k_lin0(const float* __restrict__ x,
                                              const float* __restrict__ w,
                                              const float* __restrict__ b,
                                              unsigned* __restrict__ h0, int N) {
    __shared__ float Wt[IN_C * 65];
    for (int i = threadIdx.x; i < IN_C * HID; i += 256) {
        int o = i >> 7, k = i & 127;
        Wt[k * 65 + o] = w[i];
    }
    __syncthreads();
    int lane = threadIdx.x & 63;
    int wid = (blockIdx.x * blockDim.x + threadIdx.x) >> 6;
    int nw = (gridDim.x * blockDim.x) >> 6;
    float bias = b[lane];
    for (int n0 = wid; n0 < N; n0 += 2 * nw) {
        int n1 = n0 + nw;
        bool v1 = n1 < N;
        int n1c = v1 ? n1 : n0;
        float xa0 = x[(size_t)n0 * IN_C + lane];
        float xa1 = x[(size_t)n0 * IN_C + 64 + lane];
        float xb0 = x[(size_t)n1c * IN_C + lane];
        float xb1 = x[(size_t)n1c * IN_C + 64 + lane];
        float acc0 = bias, acc1 = bias;
#pragma unroll
        for (int k = 0; k < 64; ++k) {
            float wv = Wt[k * 65 + lane];
            acc0 = fmaf(rl(xa0, k), wv, acc0);
            acc1 = fmaf(rl(xb0, k), wv, acc1);
        }
#pragma unroll
        for (int k = 0; k < 64; ++k) {
            float wv = Wt[(64 + k) * 65 + lane];
            acc0 = fmaf(rl(xa1, k), wv, acc0);
            acc1 = fmaf(rl(xb1, k), wv, acc1);
        }
        acc0 = fmaxf(acc0, 0.f);
        acc1 = fmaxf(acc1, 0.f);
        float p0 = pairswap(acc0);   // even lane <- odd neighbor's value
        float p1 = pairswap(acc1);
        if ((lane & 1) == 0) {
            h0[(size_t)n0 * 32 + (lane >> 1)] = bfpack(acc0, p0);
            if (v1) h0[(size_t)n1 * 32 + (lane >> 1)] = bfpack(acc1, p1);
        }
    }
}

// ---- fused GCN2 layer (bf16 state, LDS-pipe minimized) -------------------
// Row = 64 bf16 = 128B = 8 x uint4. Lane = (sub = lane>>3 edge slot,
// cg = lane&7 channel group of 8). Reduce over subs on VALU (DPP/permlane).
// GEMM reads W as bf16 quads via ds_read_b64 (16 LDS ops/node).
__global__ __launch_bounds__(256) void k_layer(const uint4* __restrict__ hin,
                                               const uint4* __restrict__ h0,
                                               unsigned* __restrict__ hout,
                                               const float* __restrict__ W,
                                               const int* __restrict__ row_ptr,
                                               const int* __restrict__ col_idx,
                                               float beta, int N) {
    __shared__ uint2 Wp[16 * 64];   // Wp[k4*64+c] = bf16x4 of W[4k4+0..3][c]
    __shared__ float zb[4 * 64];    // per-wave z bounce buffer
    for (int idx = threadIdx.x; idx < 16 * 64; idx += 256) {
        int k4 = idx >> 6, c = idx & 63;
        float w0 = W[(4 * k4 + 0) * 64 + c];
        float w1 = W[(4 * k4 + 1) * 64 + c];
        float w2 = W[(4 * k4 + 2) * 64 + c];
        float w3 = W[(4 * k4 + 3) * 64 + c];
        uint2 p;
        p.x = bfpack(w0, w1);
        p.y = bfpack(w2, w3);
        Wp[idx] = p;
    }
    __syncthreads();

    int lane = threadIdx.x & 63;
    int wslot = threadIdx.x >> 6;
    int sub = lane >> 3;
    int cg = lane & 7;
    int wid = (blockIdx.x * blockDim.x + threadIdx.x) >> 6;
    int nw = (gridDim.x * blockDim.x) >> 6;

    for (int n = wid; n < N; n += nw) {
        int b = row_ptr[n];
        int d = row_ptr[n + 1] - b;
        float a[8];
#pragma unroll
        for (int c = 0; c < 8; ++c) a[c] = 0.f;
        int j = 0;
        for (; j + 16 <= d; j += 16) {
            int i0 = col_idx[b + j + sub];
            int i1 = col_idx[b + j + 8 + sub];
            uint4 q0 = hin[(size_t)i0 * 8 + cg];
            uint4 q1 = hin[(size_t)i1 * 8 + cg];
            a[0] += bflo(q0.x); a[1] += bfhi(q0.x);
            a[2] += bflo(q0.y); a[3] += bfhi(q0.y);
            a[4] += bflo(q0.z); a[5] += bfhi(q0.z);
            a[6] += bflo(q0.w); a[7] += bfhi(q0.w);
            a[0] += bflo(q1.x); a[1] += bfhi(q1.x);
            a[2] += bflo(q1.y); a[3] += bfhi(q1.y);
            a[4] += bflo(q1.z); a[5] += bfhi(q1.z);
            a[6] += bflo(q1.w); a[7] += bfhi(q1.w);
        }
        if (j + sub < d) {
            int i0 = col_idx[b + j + sub];
            uint4 q0 = hin[(size_t)i0 * 8 + cg];
            a[0] += bflo(q0.x); a[1] += bfhi(q0.x);
            a[2] += bflo(q0.y); a[3] += bfhi(q0.y);
            a[4] += bflo(q0.z); a[5] += bfhi(q0.z);
            a[6] += bflo(q0.w); a[7] += bfhi(q0.w);
        }
        if (j + 8 + sub < d) {
            int i1 = col_idx[b + j + 8 + sub];
            uint4 q1 = hin[(size_t)i1 * 8 + cg];
            a[0] += bflo(q1.x); a[1] += bfhi(q1.x);
            a[2] += bflo(q1.y); a[3] += bfhi(q1.y);
            a[4] += bflo(q1.z); a[5] += bfhi(q1.z);
            a[6] += bflo(q1.w); a[7] += bfhi(q1.w);
        }
        // reduce over the 8 edge slots (lane bits 3,4,5) — all on VALU
#pragma unroll
        for (int c = 0; c < 8; ++c) a[c] = xadd8(a[c]);
#pragma unroll
        for (int c = 0; c < 8; ++c) a[c] = xadd16(a[c]);
#pragma unroll
        for (int c = 0; c < 8; ++c) a[c] = xadd32(a[c]);

        // residual
        uint4 hq = h0[(size_t)n * 8 + cg];
        float z[8];
        z[0] = 0.9f * a[0] + 0.1f * bflo(hq.x);
        z[1] = 0.9f * a[1] + 0.1f * bfhi(hq.x);
        z[2] = 0.9f * a[2] + 0.1f * bflo(hq.y);
        z[3] = 0.9f * a[3] + 0.1f * bfhi(hq.y);
        z[4] = 0.9f * a[4] + 0.1f * bflo(hq.z);
        z[5] = 0.9f * a[5] + 0.1f * bfhi(hq.z);
        z[6] = 0.9f * a[6] + 0.1f * bflo(hq.w);
        z[7] = 0.9f * a[7] + 0.1f * bfhi(hq.w);

        // bounce z through LDS to get own-channel value per lane (fp32 exact)
        if (sub == 0) {
            float4 zlo = make_float4(z[0], z[1], z[2], z[3]);
            float4 zhi = make_float4(z[4], z[5], z[6], z[7]);
            *(float4*)&zb[wslot * 64 + cg * 8]     = zlo;
            *(float4*)&zb[wslot * 64 + cg * 8 + 4] = zhi;
        }
        float zl = zb[wslot * 64 + lane];

        // GEMM: g_c = sum_k z_k * W[k][c], c = lane; W bf16-quad per ds_read_b64
        float g0 = 0.f, g1 = 0.f, g2 = 0.f, g3 = 0.f;
#pragma unroll
        for (int k4 = 0; k4 < 16; ++k4) {
            uint2 wp = Wp[k4 * 64 + lane];
            int k = 4 * k4;
            g0 = fmaf(rl(z[(k + 0) & 7], (k + 0) >> 3), bflo(wp.x), g0);
            g1 = fmaf(rl(z[(k + 1) & 7], (k + 1) >> 3), bfhi(wp.x), g1);
            g2 = fmaf(rl(z[(k + 2) & 7], (k + 2) >> 3), bflo(wp.y), g2);
            g3 = fmaf(rl(z[(k + 3) & 7], (k + 3) >> 3), bfhi(wp.y), g3);
        }
        float g = (g0 + g1) + (g2 + g3);

        float r = fmaxf((1.f - beta) * zl + beta * g, 0.f);
        float rn = pairswap(r);
        if ((lane & 1) == 0) hout[(size_t)n * 32 + (lane >> 1)] = bfpack(r, rn);
    }
}

// ---- output projection: out = h @ lin1_w^T + b --------------------------
__global__ __launch_bounds__(256) void k_lin1(const unsigned* __restrict__ h,
                                              const float* __restrict__ w,
                                              const float* __restrict__ b,
                                              float* __restrict__ out, int N) {
    __shared__ float Wt[HID * 65];
    for (int i = threadIdx.x; i < HID * HID; i += 256) {
        int o = i >> 6, k = i & 63;
        Wt[k * 65 + o] = w[i];
    }
    __syncthreads();
    int lane = threadIdx.x & 63;
    int wid = (blockIdx.x * blockDim.x + threadIdx.x) >> 6;
    int nw = (gridDim.x * blockDim.x) >> 6;
    float bias = b[lane];
    for (int n0 = wid; n0 < N; n0 += 2 * nw) {
        int n1 = n0 + nw;
        bool v1 = n1 < N;
        int n1c = v1 ? n1 : n0;
        unsigned ua = h[(size_t)n0 * 32 + (lane >> 1)];
        unsigned ub = h[(size_t)n1c * 32 + (lane >> 1)];
        float ha = (lane & 1) ? bfhi(ua) : bflo(ua);
        float hb = (lane & 1) ? bfhi(ub) : bflo(ub);
        float acc0 = bias, acc1 = bias;
#pragma unroll
        for (int k = 0; k < 64; ++k) {
            float wv = Wt[k * 65 + lane];
            acc0 = fmaf(rl(ha, k), wv, acc0);
            acc1 = fmaf(rl(hb, k), wv, acc1);
        }
        out[(size_t)n0 * HID + lane] = acc0;
        if (v1) out[(size_t)n1 * HID + lane] = acc1;
    }
}

extern "C" void kernel_launch(void* const* d_in, const int* in_sizes, int n_in,
                              void* d_out, int out_size, void* d_ws, size_t ws_size,
                              hipStream_t stream) {
    const float* x      = (const float*)d_in[0];
    const int*   ei     = (const int*)d_in[1];
    const float* lin0_w = (const float*)d_in[2];
    const float* lin0_b = (const float*)d_in[3];
    const float* lin1_w = (const float*)d_in[4];
    const float* lin1_b = (const float*)d_in[5];
    const float* conv_w = (const float*)d_in[6];

    int N = in_sizes[0] / IN_C;
    int E = in_sizes[1] / 2;
    const int* src = ei;
    const int* dst = ei + E;

    // bf16 state buffers: N*64*2B = N*32 uints each
    unsigned* h0 = (unsigned*)d_ws;
    unsigned* hA = h0 + (size_t)N * 32;
    unsigned* hB = hA + (size_t)N * 32;
    int* row_ptr    = (int*)(hB + (size_t)N * 32);
    int* cursor     = row_ptr + (N + 1);
    int* col_idx    = cursor + N;
    int* chunk_sums = col_idx + E;

    int nch = (N + 1023) / 1024;

    // CSR build
    hipMemsetAsync(cursor, 0, (size_t)N * sizeof(int), stream);
    k_hist<<<(E + 255) / 256, 256, 0, stream>>>(dst, cursor, E);
    k_scan_block<<<nch, 1024, 0, stream>>>(cursor, row_ptr, chunk_sums, N);
    k_scan_fix<<<nch, 1024, 0, stream>>>(row_ptr, chunk_sums, N, E);
    hipMemsetAsync(cursor, 0, (size_t)N * sizeof(int), stream);
    k_fill<<<(E + 255) / 256, 256, 0, stream>>>(src, dst, row_ptr, cursor, col_idx, E);

    // input projection -> h0 (bf16)
    k_lin0<<<1024, 256, 0, stream>>>(x, lin0_w, lin0_b, h0, N);

    // 16 fused layers
    const unsigned* cur = h0;
    for (int l = 0; l < 16; ++l) {
        float beta = (float)log(0.5 / (double)(l + 1) + 1.0);
        unsigned* nxt = (l & 1) ? hB : hA;
        k_layer<<<2048, 256, 0, stream>>>((const uint4*)cur, (const uint4*)h0, nxt,
                                          conv_w + (size_t)l * HID * HID,
                                          row_ptr, col_idx, beta, N);
        cur = nxt;
    }

    // output projection
    k_lin1<<<1024, 256, 0, stream>>>(cur, lin1_w, lin1_b, (float*)d_out, N);
}

// Round 7
// 1506.889 us; speedup vs baseline: 1.0026x; 1.0026x over previous
//
#include <hip/hip_runtime.h>
#include <cmath>

#define HID 64
#define IN_C 128

__device__ __forceinline__ float rl(float v, int k) {
    return __uint_as_float(__builtin_amdgcn_readlane(__float_as_uint(v), k));
}
__device__ __forceinline__ float bflo(unsigned u) { return __uint_as_float(u << 16); }
__device__ __forceinline__ float bfhi(unsigned u) { return __uint_as_float(u & 0xffff0000u); }
// pack two floats to bf16 pair with round-to-nearest-even
__device__ __forceinline__ unsigned bfpack(float lo, float hi) {
    unsigned a = __float_as_uint(lo), b = __float_as_uint(hi);
    a = (a + 0x7fffu + ((a >> 16) & 1u)) >> 16;
    b = (b + 0x7fffu + ((b >> 16) & 1u)) & 0xffff0000u;
    return a | b;
}

// ---- VALU cross-lane helpers --------------------------------------------
// xor-8 within 16-lane row: DPP row_ror:8 (0x128)
__device__ __forceinline__ float xadd8(float x) {
    int t = __builtin_amdgcn_update_dpp(0, __float_as_int(x), 0x128, 0xF, 0xF, true);
    return x + __int_as_float(t);
}
#if __has_builtin(__builtin_amdgcn_permlane16_swap)
typedef unsigned uvec2 __attribute__((ext_vector_type(2)));
__device__ __forceinline__ float xadd16(float x) {
    uvec2 r = __builtin_amdgcn_permlane16_swap(__float_as_uint(x), __float_as_uint(x), false, false);
    return __uint_as_float(r[0]) + __uint_as_float(r[1]);
}
#else
__device__ __forceinline__ float xadd16(float x) { return x + __shfl_xor(x, 16); }
#endif
#if __has_builtin(__builtin_amdgcn_permlane32_swap)
typedef unsigned uvec2b __attribute__((ext_vector_type(2)));
__device__ __forceinline__ float xadd32(float x) {
    uvec2b r = __builtin_amdgcn_permlane32_swap(__float_as_uint(x), __float_as_uint(x), false, false);
    return __uint_as_float(r[0]) + __uint_as_float(r[1]);
}
#else
__device__ __forceinline__ float xadd32(float x) { return x + __shfl_xor(x, 32); }
#endif
// value from lane^1: DPP quad_perm [1,0,3,2]
__device__ __forceinline__ float pairswap(float x) {
    int t = __builtin_amdgcn_update_dpp(0, __float_as_int(x), 0xB1, 0xF, 0xF, true);
    return __int_as_float(t);
}

// ---- CSR build ----------------------------------------------------------

__global__ void k_hist(const int* __restrict__ dst, int* __restrict__ counts, int E) {
    int e = blockIdx.x * blockDim.x + threadIdx.x;
    if (e < E) atomicAdd(&counts[dst[e]], 1);
}

__global__ void k_scan_block(const int* __restrict__ counts, int* __restrict__ row_ptr,
                             int* __restrict__ chunk_sums, int n) {
    __shared__ int s[1024];
    int i = blockIdx.x * 1024 + threadIdx.x;
    int v = (i < n) ? counts[i] : 0;
    s[threadIdx.x] = v;
    __syncthreads();
    for (int off = 1; off < 1024; off <<= 1) {
        int t = (threadIdx.x >= off) ? s[threadIdx.x - off] : 0;
        __syncthreads();
        s[threadIdx.x] += t;
        __syncthreads();
    }
    if (i < n) row_ptr[i] = s[threadIdx.x] - v;   // exclusive
    if (threadIdx.x == 1023) chunk_sums[blockIdx.x] = s[1023];
}

__global__ void k_scan_fix(int* __restrict__ row_ptr, const int* __restrict__ chunk_sums,
                           int n, int total) {
    __shared__ int base_s;
    if (threadIdx.x == 0) {
        int b = 0;
        for (int c = 0; c < (int)blockIdx.x; ++c) b += chunk_sums[c];
        base_s = b;
    }
    __syncthreads();
    int i = blockIdx.x * 1024 + threadIdx.x;
    if (i < n) row_ptr[i] += base_s;
    if (i == 0) row_ptr[n] = total;
}

__global__ void k_fill(const int* __restrict__ src, const int* __restrict__ dst,
                       const int* __restrict__ row_ptr, int* __restrict__ cursor,
                       int* __restrict__ col_idx, int E) {
    int e = blockIdx.x * blockDim.x + threadIdx.x;
    if (e < E) {
        int d = dst[e];
        int pos = row_ptr[d] + atomicAdd(&cursor[d], 1);
        col_idx[pos] = src[e];
    }
}

// ---- input projection: h0(bf16) = relu(x @ lin0_w^T) --------------------
__global__ __launch_bounds__(256) void k_lin0(const float* __restrict__ x,
                                              const float* __restrict__ w,
                                              const float* __restrict__ b,
                                              unsigned* __restrict__ h0, int N) {
    __shared__ float Wt[IN_C * 65];
    for (int i = threadIdx.x; i < IN_C * HID; i += 256) {
        int o = i >> 7, k = i & 127;
        Wt[k * 65 + o] = w[i];
    }
    __syncthreads();
    int lane = threadIdx.x & 63;
    int wid = (blockIdx.x * blockDim.x + threadIdx.x) >> 6;
    int nw = (gridDim.x * blockDim.x) >> 6;
    float bias = b[lane];
    for (int n0 = wid; n0 < N; n0 += 2 * nw) {
        int n1 = n0 + nw;
        bool v1 = n1 < N;
        int n1c = v1 ? n1 : n0;
        float xa0 = x[(size_t)n0 * IN_C + lane];
        float xa1 = x[(size_t)n0 * IN_C + 64 + lane];
        float xb0 = x[(size_t)n1c * IN_C + lane];
        float xb1 = x[(size_t)n1c * IN_C + 64 + lane];
        float acc0 = bias, acc1 = bias;
#pragma unroll
        for (int k = 0; k < 64; ++k) {
            float wv = Wt[k * 65 + lane];
            acc0 = fmaf(rl(xa0, k), wv, acc0);
            acc1 = fmaf(rl(xb0, k), wv, acc1);
        }
#pragma unroll
        for (int k = 0; k < 64; ++k) {
            float wv = Wt[(64 + k) * 65 + lane];
            acc0 = fmaf(rl(xa1, k), wv, acc0);
            acc1 = fmaf(rl(xb1, k), wv, acc1);
        }
        acc0 = fmaxf(acc0, 0.f);
        acc1 = fmaxf(acc1, 0.f);
        float p0 = pairswap(acc0);
        float p1 = pairswap(acc1);
        if ((lane & 1) == 0) {
            h0[(size_t)n0 * 32 + (lane >> 1)] = bfpack(acc0, p0);
            if (v1) h0[(size_t)n1 * 32 + (lane >> 1)] = bfpack(acc1, p1);
        }
    }
}

// ---- fused GCN2 layer ----------------------------------------------------
// W' = (1-beta)I + beta*W folded (no z extraction/bounce needed).
// 2 nodes per wave iteration; gather rounds use clamped indices + cndmask
// masking so 4 col_idx + 4 row loads (4 KB) issue unconditionally per iter.
__device__ __forceinline__ void mask4(uint4& q, bool v) {
    q.x = v ? q.x : 0u; q.y = v ? q.y : 0u; q.z = v ? q.z : 0u; q.w = v ? q.w : 0u;
}
__device__ __forceinline__ void acc8(float* a, const uint4& q) {
    a[0] += bflo(q.x); a[1] += bfhi(q.x);
    a[2] += bflo(q.y); a[3] += bfhi(q.y);
    a[4] += bflo(q.z); a[5] += bfhi(q.z);
    a[6] += bflo(q.w); a[7] += bfhi(q.w);
}

__global__ __launch_bounds__(256) void k_layer(const uint4* __restrict__ hin,
                                               const uint4* __restrict__ h0,
                                               unsigned* __restrict__ hout,
                                               const float* __restrict__ W,
                                               const int* __restrict__ row_ptr,
                                               const int* __restrict__ col_idx,
                                               float beta, int N, int E) {
    __shared__ uint4 Wp[8 * 64];   // Wp[k8*64+c] = bf16x8 of W'[8k8+0..7][c]
    for (int idx = threadIdx.x; idx < 8 * 64; idx += 256) {
        int k8 = idx >> 6, c = idx & 63;
        float wv[8];
#pragma unroll
        for (int m = 0; m < 8; ++m) {
            int k = 8 * k8 + m;
            float v = beta * W[k * 64 + c];
            if (k == c) v += 1.f - beta;
            wv[m] = v;
        }
        uint4 p;
        p.x = bfpack(wv[0], wv[1]); p.y = bfpack(wv[2], wv[3]);
        p.z = bfpack(wv[4], wv[5]); p.w = bfpack(wv[6], wv[7]);
        Wp[idx] = p;
    }
    __syncthreads();

    int lane = threadIdx.x & 63;
    int sub = lane >> 3;
    int cg = lane & 7;
    int wid = (blockIdx.x * blockDim.x + threadIdx.x) >> 6;
    int nw = (gridDim.x * blockDim.x) >> 6;

    for (int n = wid; n < N; n += 2 * nw) {
        int nB = n + nw;
        bool vB = nB < N;
        int nBc = vB ? nB : n;
        int bA = row_ptr[n];
        int dA = row_ptr[n + 1] - bA;
        int bB = row_ptr[nBc];
        int dB = vB ? row_ptr[nBc + 1] - bB : 0;
        uint4 hqA = h0[(size_t)n * 8 + cg];     // residual rows, issued early
        uint4 hqB = h0[(size_t)nBc * 8 + cg];
        int lastA = max(bA + dA - 1, 0);
        int lastB = max(bB + dB - 1, 0);
        float aA[8], aB[8];
#pragma unroll
        for (int c = 0; c < 8; ++c) { aA[c] = 0.f; aB[c] = 0.f; }
        int rmax = max(dA, dB);
        for (int j = 0; j < rmax; j += 16) {
            int p0 = j + sub, p1 = j + 8 + sub;
            int iA0 = col_idx[min(bA + p0, lastA)];
            int iA1 = col_idx[min(bA + p1, lastA)];
            int iB0 = col_idx[min(bB + p0, lastB)];
            int iB1 = col_idx[min(bB + p1, lastB)];
            uint4 qA0 = hin[(size_t)iA0 * 8 + cg];
            uint4 qA1 = hin[(size_t)iA1 * 8 + cg];
            uint4 qB0 = hin[(size_t)iB0 * 8 + cg];
            uint4 qB1 = hin[(size_t)iB1 * 8 + cg];
            mask4(qA0, p0 < dA); mask4(qA1, p1 < dA);
            mask4(qB0, p0 < dB); mask4(qB1, p1 < dB);
            acc8(aA, qA0); acc8(aA, qA1);
            acc8(aB, qB0); acc8(aB, qB1);
        }
        // reduce over the 8 edge slots — VALU only
#pragma unroll
        for (int c = 0; c < 8; ++c) { aA[c] = xadd8(aA[c]);  aB[c] = xadd8(aB[c]); }
#pragma unroll
        for (int c = 0; c < 8; ++c) { aA[c] = xadd16(aA[c]); aB[c] = xadd16(aB[c]); }
#pragma unroll
        for (int c = 0; c < 8; ++c) { aA[c] = xadd32(aA[c]); aB[c] = xadd32(aB[c]); }

        // residual: z = 0.9*agg + 0.1*h0  (channel 8*cg+c on register c)
        float zA[8], zB[8];
        zA[0] = 0.9f * aA[0] + 0.1f * bflo(hqA.x);
        zA[1] = 0.9f * aA[1] + 0.1f * bfhi(hqA.x);
        zA[2] = 0.9f * aA[2] + 0.1f * bflo(hqA.y);
        zA[3] = 0.9f * aA[3] + 0.1f * bfhi(hqA.y);
        zA[4] = 0.9f * aA[4] + 0.1f * bflo(hqA.z);
        zA[5] = 0.9f * aA[5] + 0.1f * bfhi(hqA.z);
        zA[6] = 0.9f * aA[6] + 0.1f * bflo(hqA.w);
        zA[7] = 0.9f * aA[7] + 0.1f * bfhi(hqA.w);
        zB[0] = 0.9f * aB[0] + 0.1f * bflo(hqB.x);
        zB[1] = 0.9f * aB[1] + 0.1f * bfhi(hqB.x);
        zB[2] = 0.9f * aB[2] + 0.1f * bflo(hqB.y);
        zB[3] = 0.9f * aB[3] + 0.1f * bfhi(hqB.y);
        zB[4] = 0.9f * aB[4] + 0.1f * bflo(hqB.z);
        zB[5] = 0.9f * aB[5] + 0.1f * bfhi(hqB.z);
        zB[6] = 0.9f * aB[6] + 0.1f * bflo(hqB.w);
        zB[7] = 0.9f * aB[7] + 0.1f * bfhi(hqB.w);

        // r_c = sum_k z_k * W'[k][c], c = lane. z_{8k8+m} = rl(z[m], k8).
        float gA0 = 0.f, gA1 = 0.f, gA2 = 0.f, gA3 = 0.f;
        float gB0 = 0.f, gB1 = 0.f, gB2 = 0.f, gB3 = 0.f;
#pragma unroll
        for (int k8 = 0; k8 < 8; ++k8) {
            uint4 wp = Wp[k8 * 64 + lane];
            gA0 = fmaf(rl(zA[0], k8), bflo(wp.x), gA0);
            gA1 = fmaf(rl(zA[1], k8), bfhi(wp.x), gA1);
            gA2 = fmaf(rl(zA[2], k8), bflo(wp.y), gA2);
            gA3 = fmaf(rl(zA[3], k8), bfhi(wp.y), gA3);
            gA0 = fmaf(rl(zA[4], k8), bflo(wp.z), gA0);
            gA1 = fmaf(rl(zA[5], k8), bfhi(wp.z), gA1);
            gA2 = fmaf(rl(zA[6], k8), bflo(wp.w), gA2);
            gA3 = fmaf(rl(zA[7], k8), bfhi(wp.w), gA3);
            gB0 = fmaf(rl(zB[0], k8), bflo(wp.x), gB0);
            gB1 = fmaf(rl(zB[1], k8), bfhi(wp.x), gB1);
            gB2 = fmaf(rl(zB[2], k8), bflo(wp.y), gB2);
            gB3 = fmaf(rl(zB[3], k8), bfhi(wp.y), gB3);
            gB0 = fmaf(rl(zB[4], k8), bflo(wp.z), gB0);
            gB1 = fmaf(rl(zB[5], k8), bfhi(wp.z), gB1);
            gB2 = fmaf(rl(zB[6], k8), bflo(wp.w), gB2);
            gB3 = fmaf(rl(zB[7], k8), bfhi(wp.w), gB3);
        }
        float rA = fmaxf((gA0 + gA1) + (gA2 + gA3), 0.f);
        float rB = fmaxf((gB0 + gB1) + (gB2 + gB3), 0.f);
        float rAn = pairswap(rA);
        float rBn = pairswap(rB);
        if ((lane & 1) == 0) {
            hout[(size_t)n * 32 + (lane >> 1)] = bfpack(rA, rAn);
            if (vB) hout[(size_t)nB * 32 + (lane >> 1)] = bfpack(rB, rBn);
        }
    }
}

// ---- output projection: out = h @ lin1_w^T + b --------------------------
__global__ __launch_bounds__(256) void k_lin1(const unsigned* __restrict__ h,
                                              const float* __restrict__ w,
                                              const float* __restrict__ b,
                                              float* __restrict__ out, int N) {
    __shared__ float Wt[HID * 65];
    for (int i = threadIdx.x; i < HID * HID; i += 256) {
        int o = i >> 6, k = i & 63;
        Wt[k * 65 + o] = w[i];
    }
    __syncthreads();
    int lane = threadIdx.x & 63;
    int wid = (blockIdx.x * blockDim.x + threadIdx.x) >> 6;
    int nw = (gridDim.x * blockDim.x) >> 6;
    float bias = b[lane];
    for (int n0 = wid; n0 < N; n0 += 2 * nw) {
        int n1 = n0 + nw;
        bool v1 = n1 < N;
        int n1c = v1 ? n1 : n0;
        unsigned ua = h[(size_t)n0 * 32 + (lane >> 1)];
        unsigned ub = h[(size_t)n1c * 32 + (lane >> 1)];
        float ha = (lane & 1) ? bfhi(ua) : bflo(ua);
        float hb = (lane & 1) ? bfhi(ub) : bflo(ub);
        float acc0 = bias, acc1 = bias;
#pragma unroll
        for (int k = 0; k < 64; ++k) {
            float wv = Wt[k * 65 + lane];
            acc0 = fmaf(rl(ha, k), wv, acc0);
            acc1 = fmaf(rl(hb, k), wv, acc1);
        }
        out[(size_t)n0 * HID + lane] = acc0;
        if (v1) out[(size_t)n1 * HID + lane] = acc1;
    }
}

extern "C" void kernel_launch(void* const* d_in, const int* in_sizes, int n_in,
                              void* d_out, int out_size, void* d_ws, size_t ws_size,
                              hipStream_t stream) {
    const float* x      = (const float*)d_in[0];
    const int*   ei     = (const int*)d_in[1];
    const float* lin0_w = (const float*)d_in[2];
    const float* lin0_b = (const float*)d_in[3];
    const float* lin1_w = (const float*)d_in[4];
    const float* lin1_b = (const float*)d_in[5];
    const float* conv_w = (const float*)d_in[6];

    int N = in_sizes[0] / IN_C;
    int E = in_sizes[1] / 2;
    const int* src = ei;
    const int* dst = ei + E;

    // bf16 state buffers: N*64*2B = N*32 uints each
    unsigned* h0 = (unsigned*)d_ws;
    unsigned* hA = h0 + (size_t)N * 32;
    unsigned* hB = hA + (size_t)N * 32;
    int* row_ptr    = (int*)(hB + (size_t)N * 32);
    int* cursor     = row_ptr + (N + 1);
    int* col_idx    = cursor + N;
    int* chunk_sums = col_idx + E;

    int nch = (N + 1023) / 1024;

    // CSR build
    hipMemsetAsync(cursor, 0, (size_t)N * sizeof(int), stream);
    k_hist<<<(E + 255) / 256, 256, 0, stream>>>(dst, cursor, E);
    k_scan_block<<<nch, 1024, 0, stream>>>(cursor, row_ptr, chunk_sums, N);
    k_scan_fix<<<nch, 1024, 0, stream>>>(row_ptr, chunk_sums, N, E);
    hipMemsetAsync(cursor, 0, (size_t)N * sizeof(int), stream);
    k_fill<<<(E + 255) / 256, 256, 0, stream>>>(src, dst, row_ptr, cursor, col_idx, E);

    // input projection -> h0 (bf16)
    k_lin0<<<1024, 256, 0, stream>>>(x, lin0_w, lin0_b, h0, N);

    // 16 fused layers
    const unsigned* cur = h0;
    for (int l = 0; l < 16; ++l) {
        float beta = (float)log(0.5 / (double)(l + 1) + 1.0);
        unsigned* nxt = (l & 1) ? hB : hA;
        k_layer<<<2048, 256, 0, stream>>>((const uint4*)cur, (const uint4*)h0, nxt,
                                          conv_w + (size_t)l * HID * HID,
                                          row_ptr, col_idx, beta, N, E);
        cur = nxt;
    }

    // output projection
    k_lin1<<<1024, 256, 0, stream>>>(cur, lin1_w, lin1_b, (float*)d_out, N);
}